// Round 5
// baseline (1535.322 us; speedup 1.0000x reference)
//
#include <hip/hip_runtime.h>

#define D 128
#define SRCBITS 17          // 100000 < 2^17
#define SRCMASK ((1 << SRCBITS) - 1)
#define CBITS 8             // 256 nodes per coarse bucket
#define CNODES 256
#define CHUNK 4096          // edges per hist/scatter block

typedef __attribute__((ext_vector_type(8))) short short8;
typedef __attribute__((ext_vector_type(4))) float f32x4;

// f32 -> bf16 round-to-nearest-even
static __device__ __forceinline__ unsigned short f2bf(float f) {
    unsigned u = __float_as_uint(f);
    unsigned r = (u + 0x7FFFu + ((u >> 16) & 1u)) >> 16;
    return (unsigned short)r;
}
static __device__ __forceinline__ float bf2f(unsigned short b) {
    return __uint_as_float(((unsigned)b) << 16);
}

// ===========================================================================
// A. coarse histogram: ccount[b] = #edges with (dst>>8)==b. LDS-staged.
// ===========================================================================
__global__ __launch_bounds__(256) void coarse_hist(
    const int* __restrict__ edst, int* __restrict__ ccount, int nE, int NB)
{
    __shared__ int lh[512];
    int t = threadIdx.x;
    for (int i = t; i < 512; i += 256) lh[i] = 0;
    __syncthreads();
    int e0 = blockIdx.x * CHUNK;
    int eend = e0 + CHUNK < nE ? e0 + CHUNK : nE;
    for (int e = e0 + t; e < eend; e += 256) atomicAdd(&lh[edst[e] >> CBITS], 1);
    __syncthreads();
    for (int i = t; i < NB; i += 256) {
        int v = lh[i];
        if (v > 0) atomicAdd(&ccount[i], v);
    }
}

// ===========================================================================
// B. scan over NB (<=512) buckets -> cstart[NB+1], ccur init. Single block.
// ===========================================================================
__global__ __launch_bounds__(512) void coarse_scan(
    const int* __restrict__ ccount, int* __restrict__ cstart,
    int* __restrict__ ccur, int NB, int nE)
{
    __shared__ int tmp[512];
    int t = threadIdx.x;
    tmp[t] = (t < NB) ? ccount[t] : 0;
    __syncthreads();
    for (int off = 1; off < 512; off <<= 1) {
        int v = (t >= off) ? tmp[t - off] : 0;
        __syncthreads();
        tmp[t] += v;
        __syncthreads();
    }
    if (t < NB) {
        int ex = (t == 0) ? 0 : tmp[t - 1];
        cstart[t] = ex;
        ccur[t]   = ex;
    }
    if (t == 0) cstart[NB] = nE;
}

// ===========================================================================
// C. bucket scatter, two-pass (no LDS staging; edge arrays are L2-hot).
//    Writes epack grouped by 256-node coarse bucket; runs of ~10 edges per
//    (block,bucket) are written in one burst -> lines complete in L2.
//    Payload: int2( src | (dst&255)<<17 , bits(w) ).
// ===========================================================================
__global__ __launch_bounds__(256) void bucket_scatter(
    const int* __restrict__ esrc, const int* __restrict__ edst,
    const float* __restrict__ ew, int* __restrict__ ccur,
    int2* __restrict__ epack, int nE)
{
    __shared__ int lhist[512];
    __shared__ int lbase[512];
    __shared__ int lcur[512];
    __shared__ int delta[512];

    int t = threadIdx.x;
    for (int i = t; i < 512; i += 256) lhist[i] = 0;
    __syncthreads();

    int e0 = blockIdx.x * CHUNK;
    int eend = e0 + CHUNK < nE ? e0 + CHUNK : nE;

    // pass 1: local histogram
    for (int e = e0 + t; e < eend; e += 256)
        atomicAdd(&lhist[edst[e] >> CBITS], 1);
    __syncthreads();

    // inclusive scan of 512 (2 slots/thread; read-sync-write per step)
    for (int off = 1; off < 512; off <<= 1) {
        int i0 = t, i1 = t + 256;
        int v0 = (i0 >= off) ? lhist[i0 - off] : 0;
        int v1 = (i1 >= off) ? lhist[i1 - off] : 0;
        __syncthreads();
        lhist[i0] += v0;
        lhist[i1] += v1;
        __syncthreads();
    }
    for (int i = t; i < 512; i += 256) {
        int ex = (i == 0) ? 0 : lhist[i - 1];
        lbase[i] = ex;
        lcur[i]  = ex;
    }
    __syncthreads();

    // reserve global runs (1 atomic per non-empty (block,bucket))
    for (int b = t; b < 512; b += 256) {
        int cnt = lhist[b] - lbase[b];
        if (cnt > 0) delta[b] = atomicAdd(&ccur[b], cnt) - lbase[b];
    }
    __syncthreads();

    // pass 2: re-read edges, write into reserved runs
    for (int e = e0 + t; e < eend; e += 256) {
        int d = edst[e];
        int b = d >> CBITS;
        int p = atomicAdd(&lcur[b], 1);
        epack[delta[b] + p] = make_int2(esrc[e] | ((d & (CNODES - 1)) << SRCBITS),
                                        __float_as_int(ew[e]));
    }
}

// ===========================================================================
// D. GEMM (MFMA bf16): x = h @ W, fp32 accumulate, bf16 store to ws.
//    Block: 64 rows, 4 waves; wave w -> rows [w*16, w*16+16), cols 0..127.
//    sW[n][k] (W transposed) and sA[row][k], both bf16, XOR-swizzled
//    (k ^ ((row&7)<<3) in ushorts) so ds_read_b128 fragments are ~conflict-free.
//    Frag layout (16x16x32): A row=lane&15, k=(lane>>4)*8+j (8 contiguous);
//    B col=lane&15, same k; D col=lane&15, row=(lane>>4)*4+reg (m89-verified).
// ===========================================================================
__global__ __launch_bounds__(256) void gemm_mfma_bf16(
    const float* __restrict__ h, const float* __restrict__ W,
    unsigned short* __restrict__ xb, int N)
{
    __shared__ unsigned short sW[128 * 128];  // 32 KB, [n][k] swizzled
    __shared__ unsigned short sA[64 * 128];   // 16 KB, [row][k] swizzled

    int t  = threadIdx.x;
    int r0 = blockIdx.x * 64;

    // stage W: read [k][n] coalesced, write transposed+swizzled
#pragma unroll
    for (int it = 0; it < 16; ++it) {
        int idx = t + it * 256;            // float4 index in [0,4096)
        int k   = idx >> 5;
        int n4  = (idx & 31) << 2;
        float4 wv = *reinterpret_cast<const float4*>(W + (size_t)k * D + n4);
        unsigned short q[4] = { f2bf(wv.x), f2bf(wv.y), f2bf(wv.z), f2bf(wv.w) };
#pragma unroll
        for (int j = 0; j < 4; ++j) {
            int n = n4 + j;
            sW[n * 128 + (k ^ ((n & 7) << 3))] = q[j];
        }
    }
    // stage A rows r0..r0+63 (clamp tail; clamped rows unused)
#pragma unroll
    for (int it = 0; it < 8; ++it) {
        int idx = t + it * 256;            // float4 index in [0,2048)
        int row = idx >> 5;
        int k4  = (idx & 31) << 2;
        int gr  = r0 + row;
        int grc = gr < N ? gr : N - 1;
        float4 av = *reinterpret_cast<const float4*>(h + (size_t)grc * D + k4);
        ushort4 q;
        q.x = f2bf(av.x); q.y = f2bf(av.y); q.z = f2bf(av.z); q.w = f2bf(av.w);
        *reinterpret_cast<ushort4*>(&sA[row * 128 + (k4 ^ ((row & 7) << 3))]) = q;
    }
    __syncthreads();

    int wv_  = t >> 6;        // wave 0..3
    int lane = t & 63;
    int wr0  = wv_ * 16;
    int l15  = lane & 15;
    int kg   = lane >> 4;     // 0..3

    f32x4 acc[8];
#pragma unroll
    for (int nt = 0; nt < 8; ++nt) acc[nt] = (f32x4){0.f, 0.f, 0.f, 0.f};

#pragma unroll
    for (int ks = 0; ks < 4; ++ks) {
        int kus = ks * 32 + kg * 8;
        int ar  = wr0 + l15;
        short8 afrag = *reinterpret_cast<const short8*>(
            &sA[ar * 128 + (kus ^ ((ar & 7) << 3))]);
#pragma unroll
        for (int nt = 0; nt < 8; ++nt) {
            int n = nt * 16 + l15;
            short8 bfrag = *reinterpret_cast<const short8*>(
                &sW[n * 128 + (kus ^ ((n & 7) << 3))]);
            acc[nt] = __builtin_amdgcn_mfma_f32_16x16x32_bf16(afrag, bfrag, acc[nt], 0, 0, 0);
        }
    }

    // epilogue: D row = wr0 + kg*4 + reg, col = nt*16 + l15
#pragma unroll
    for (int nt = 0; nt < 8; ++nt) {
#pragma unroll
        for (int reg = 0; reg < 4; ++reg) {
            int row = r0 + wr0 + kg * 4 + reg;
            if (row < N) xb[(size_t)row * D + nt * 16 + l15] = f2bf(acc[nt][reg]);
        }
    }
}

// ===========================================================================
// E. gather, edge-parallel with LDS fp32 accumulation (no sort, no atomics
//    to global). Block b2 owns 128 nodes (half of coarse bucket b2>>1), LDS
//    accumulator 128x128 f32 = 64 KB. One wave per edge: epack addr is
//    wave-uniform; 64 lanes each handle cols {lane, lane+64}; ds_add_f32 at
//    bank=lane%32 -> 2-way (free). All x-row loads independent -> MLP.
// ===========================================================================
__global__ __launch_bounds__(512) void bucket_gather(
    const unsigned short* __restrict__ xb, const int* __restrict__ cstart,
    const int2* __restrict__ epack, const float* __restrict__ bias,
    float* __restrict__ out, int N)
{
    __shared__ float acc[128 * 128];  // 64 KB

    int t    = threadIdx.x;
    int b2   = blockIdx.x;
    int cb   = b2 >> 1;
    int half = b2 & 1;
    int n0   = b2 * 128;

    // zero accumulator
#pragma unroll
    for (int i = t; i < 128 * 32; i += 512)
        *reinterpret_cast<float4*>(&acc[i * 4]) = make_float4(0.f, 0.f, 0.f, 0.f);
    __syncthreads();

    int rbeg = cstart[cb];
    int rend = cstart[cb + 1];
    int wave = t >> 6;
    int lane = t & 63;

    for (int i = rbeg + wave; i < rend; i += 8) {
        int2 v = epack[i];                       // wave-uniform address
        int dl = (v.x >> SRCBITS) & (CNODES - 1);
        if ((dl >> 7) != half) continue;         // wave-uniform branch
        int   src = v.x & SRCMASK;
        float w   = __int_as_float(v.y);
        const unsigned short* xr = xb + (size_t)src * D + lane;
        float x0 = bf2f(xr[0]);
        float x1 = bf2f(xr[64]);
        int a0 = ((dl & 127) << 7) + lane;
        atomicAdd(&acc[a0],      w * x0);
        atomicAdd(&acc[a0 + 64], w * x1);
    }
    __syncthreads();

    // epilogue: out = relu(acc + bias)
    for (int i = t; i < 128 * 32; i += 512) {
        int row  = i >> 5;
        int c4   = (i & 31) << 2;
        int node = n0 + row;
        if (node < N) {
            float4 a  = *reinterpret_cast<float4*>(&acc[(row << 7) + c4]);
            float4 bb = *reinterpret_cast<const float4*>(bias + c4);
            float4 o;
            o.x = fmaxf(a.x + bb.x, 0.f);
            o.y = fmaxf(a.y + bb.y, 0.f);
            o.z = fmaxf(a.z + bb.z, 0.f);
            o.w = fmaxf(a.w + bb.w, 0.f);
            *reinterpret_cast<float4*>(out + (size_t)node * D + c4) = o;
        }
    }
}

// ===========================================================================
// Fallback path (ws too small): atomic scatter + in-place fp32 GEMM+epilogue
// ===========================================================================
__global__ __launch_bounds__(256) void gcn_scatter(
    const float* __restrict__ h, const int* __restrict__ esrc,
    const int* __restrict__ edst, const float* __restrict__ ew,
    float* __restrict__ agg, int nE)
{
    long long tid = (long long)blockIdx.x * 256 + threadIdx.x;
    int e = (int)(tid >> 5);
    if (e >= nE) return;
    int c = ((int)tid & 31) << 2;
    int s = esrc[e];
    int d = edst[e];
    float w = ew[e];
    const float4 hv = *reinterpret_cast<const float4*>(h + (size_t)s * D + c);
    float* o = agg + (size_t)d * D + c;
    atomicAdd(o + 0, hv.x * w);
    atomicAdd(o + 1, hv.y * w);
    atomicAdd(o + 2, hv.z * w);
    atomicAdd(o + 3, hv.w * w);
}

__global__ __launch_bounds__(256) void gcn_gemm_bias_relu(
    const float* __restrict__ A, const float* __restrict__ W,
    const float* __restrict__ bias, float* __restrict__ out, int N)
{
    __shared__ float sA[32][64];
    __shared__ float sB[32][128];
    int t  = threadIdx.x;
    int tx = t & 31;
    int ty = t >> 5;
    int r0 = blockIdx.x * 64;
    float4 acc[8];
#pragma unroll
    for (int i = 0; i < 8; ++i) acc[i] = make_float4(0.f, 0.f, 0.f, 0.f);
    for (int kc = 0; kc < 4; ++kc) {
#pragma unroll
        for (int it = 0; it < 2; ++it) {
            int r    = (t >> 3) + it * 32;
            int kk   = (t & 7) * 4;
            int row  = r0 + r;
            int rowc = row < N ? row : N - 1;
            float4 v = *reinterpret_cast<const float4*>(
                A + (size_t)rowc * D + kc * 32 + kk);
            sA[kk + 0][r] = v.x;
            sA[kk + 1][r] = v.y;
            sA[kk + 2][r] = v.z;
            sA[kk + 3][r] = v.w;
        }
#pragma unroll
        for (int it = 0; it < 4; ++it) {
            int g  = t + it * 256;
            int k  = g >> 5;
            int cc = (g & 31) * 4;
            *reinterpret_cast<float4*>(&sB[k][cc]) =
                *reinterpret_cast<const float4*>(W + (size_t)(kc * 32 + k) * D + cc);
        }
        __syncthreads();
#pragma unroll
        for (int kk = 0; kk < 32; ++kk) {
            float4 bv = *reinterpret_cast<const float4*>(&sB[kk][tx * 4]);
#pragma unroll
            for (int i = 0; i < 8; ++i) {
                float a = sA[kk][ty * 8 + i];
                acc[i].x += a * bv.x;
                acc[i].y += a * bv.y;
                acc[i].z += a * bv.z;
                acc[i].w += a * bv.w;
            }
        }
        __syncthreads();
    }
    float4 bb = *reinterpret_cast<const float4*>(bias + tx * 4);
#pragma unroll
    for (int i = 0; i < 8; ++i) {
        int row = r0 + ty * 8 + i;
        if (row < N) {
            float4 v;
            v.x = fmaxf(acc[i].x + bb.x, 0.f);
            v.y = fmaxf(acc[i].y + bb.y, 0.f);
            v.z = fmaxf(acc[i].z + bb.z, 0.f);
            v.w = fmaxf(acc[i].w + bb.w, 0.f);
            *reinterpret_cast<float4*>(out + (size_t)row * D + tx * 4) = v;
        }
    }
}

// ---------------------------------------------------------------------------
extern "C" void kernel_launch(void* const* d_in, const int* in_sizes, int n_in,
                              void* d_out, int out_size, void* d_ws, size_t ws_size,
                              hipStream_t stream)
{
    const float* h    = (const float*)d_in[0];
    const int*   esrc = (const int*)  d_in[1];
    const int*   edst = (const int*)  d_in[2];
    const float* ew   = (const float*)d_in[3];
    const float* W    = (const float*)d_in[4];
    const float* bias = (const float*)d_in[5];
    float* out = (float*)d_out;

    const int nE = in_sizes[1];
    const int N  = in_sizes[0] / D;
    const int NB = (N + CNODES - 1) / CNODES;     // coarse buckets

    // ws layout: ccount[NB] | cstart[NB+1] | ccur[NB] | epack[E] int2 | xb[N*D] bf16
    char* base = (char*)d_ws;
    size_t intBytes = ((size_t)NB + (NB + 1) + NB) * 4;
    size_t o1 = (intBytes + 15) & ~(size_t)15;
    size_t o2 = (o1 + (size_t)nE * 8 + 15) & ~(size_t)15;
    size_t need = o2 + (size_t)N * D * 2;

    if (ws_size >= need && NB <= 512) {
        int*  ccount = (int*)base;
        int*  cstart = ccount + NB;
        int*  ccur   = cstart + (NB + 1);
        int2* epack  = (int2*)(base + o1);
        unsigned short* xb = (unsigned short*)(base + o2);

        hipMemsetAsync(ccount, 0, (size_t)NB * sizeof(int), stream);

        int eBlocks = (nE + CHUNK - 1) / CHUNK;
        coarse_hist<<<eBlocks, 256, 0, stream>>>(edst, ccount, nE, NB);
        coarse_scan<<<1, 512, 0, stream>>>(ccount, cstart, ccur, NB, nE);
        bucket_scatter<<<eBlocks, 256, 0, stream>>>(esrc, edst, ew, ccur, epack, nE);

        int gemmBlocks = (N + 63) / 64;
        gemm_mfma_bf16<<<gemmBlocks, 256, 0, stream>>>(h, W, xb, N);

        int gBlocks = (N + 127) / 128;
        bucket_gather<<<gBlocks, 512, 0, stream>>>(xb, cstart, epack, bias, out, N);
    } else {
        hipMemsetAsync(d_out, 0, (size_t)out_size * sizeof(float), stream);
        long long scatterThreads = (long long)nE * 32;
        int scatterBlocks = (int)((scatterThreads + 255) / 256);
        gcn_scatter<<<scatterBlocks, 256, 0, stream>>>(h, esrc, edst, ew, out, nE);
        int gemmBlocks = (N + 63) / 64;
        gcn_gemm_bias_relu<<<gemmBlocks, 256, 0, stream>>>(out, W, bias, out, N);
    }
}